// Round 1
// baseline (665.564 us; speedup 1.0000x reference)
//
#include <hip/hip_runtime.h>

// out[b, r, c] = (c >= r) ? in[b, triu_index(r, c)] : 0
// triu_index(r,c) = r*M - r*(r-1)/2 + (c - r)   (np.triu_indices row-major order)

constexpr int M = 1024;
constexpr int BATCH = 128;
constexpr int TRIU_LEN = M * (M + 1) / 2;  // 524800
constexpr int QUADS_PER_ROW = M / 4;       // 256

__global__ __launch_bounds__(256) void triu_scatter_kernel(
    const float* __restrict__ in, float* __restrict__ out) {
    // One thread per 4 consecutive output columns (one float4 store).
    int tid = blockIdx.x * blockDim.x + threadIdx.x;  // 0 .. B*M*256-1 (33.5M, fits int)
    int qc = tid & (QUADS_PER_ROW - 1);   // quad within row
    int r  = (tid >> 8) & (M - 1);        // row
    int b  = tid >> 18;                   // batch
    int c0 = qc << 2;

    // input index for column c of row r: row_base + c
    int row_base = r * M - (r * (r - 1)) / 2 - r;
    const float* inb = in + (long)b * TRIU_LEN + row_base;

    float4 v;
    if (c0 >= r) {
        // whole quad in upper triangle — contiguous dword reads, coalesced
        v.x = inb[c0];
        v.y = inb[c0 + 1];
        v.z = inb[c0 + 2];
        v.w = inb[c0 + 3];
    } else if (c0 + 3 < r) {
        // whole quad strictly below diagonal
        v = make_float4(0.f, 0.f, 0.f, 0.f);
    } else {
        // boundary quad (at most one per row)
        v.x = (c0     >= r) ? inb[c0]     : 0.f;
        v.y = (c0 + 1 >= r) ? inb[c0 + 1] : 0.f;
        v.z = (c0 + 2 >= r) ? inb[c0 + 2] : 0.f;
        v.w = (c0 + 3 >= r) ? inb[c0 + 3] : 0.f;
    }

    reinterpret_cast<float4*>(out)[tid] = v;
}

extern "C" void kernel_launch(void* const* d_in, const int* in_sizes, int n_in,
                              void* d_out, int out_size, void* d_ws, size_t ws_size,
                              hipStream_t stream) {
    const float* in = (const float*)d_in[0];
    float* out = (float*)d_out;

    const int total_quads = BATCH * M * QUADS_PER_ROW;  // 33,554,432
    const int block = 256;
    const int grid = total_quads / block;  // 131072

    triu_scatter_kernel<<<grid, block, 0, stream>>>(in, out);
}